// Round 10
// baseline (177.368 us; speedup 1.0000x reference)
//
#include <hip/hip_runtime.h>

// ---------------------------------------------------------------------------
// KCL: per-edge weighted current, scatter (+dst, -src), mean(node_sum^2).
//
// R10 (plan T): split the scan into
//   1) kcl_wpass: pure gather+math kernel -> bf16 w[E] (no LDS/ballot, max TLP)
//   2) kcl_scanM: record machinery only (bit-splice bf16 w into records,
//      no gathers, no float math)
// Rationale: R6/R9 falsified VALU/occupancy/pipelining for the fused scan;
// model says it's divergent-gather request throughput (~4-5 cyc/lane-req).
// Splitting isolates the two costs into separate dispatches (attribution)
// and removes port interference. bin/reduce unchanged (proven).
//
// Inputs (harness converts integer inputs to int32):
//   d_in[0] node_features float32 [N,4] (cols 0,1), d_in[1] edge_index int32 [2,E]
//   d_in[2] edge_probs float32 [E],  d_in[3] edge_params float32 [E,2]
// ---------------------------------------------------------------------------

#define EPS 1e-6f

// ---- plan T/S geometry ----
#define NPASS       4
#define S_BLOCKS    1024
#define S_THREADS   512
#define S_WPB       (S_THREADS / 64)     // 8 waves/block
#define NWAVE       (S_BLOCKS * S_WPB)   // 8192
#define RING        320                  // LDS ring slots per (wave,bucket)
#define CAP         472                  // records per (wave,bucket) segment
#define RPP         64                   // bin blocks per pass
#define BIN_THREADS 1024
#define B1MAX       25600

typedef unsigned long long ull;

__device__ __forceinline__ float edge_wc(const float* __restrict__ nf,
                                         int s, int d, float R, float X, float p)
{
    float2 vs = *(const float2*)(nf + ((size_t)s << 2));
    float2 vd = *(const float2*)(nf + ((size_t)d << 2));
    float dr = vs.x - vd.x;
    float di = vs.y - vd.y;
    float rr = R + EPS;
    return sqrtf(dr * dr + di * di) * rsqrtf(rr * rr + X * X) * p;
}

// base clamp (512 >= CAP) keeps ring-mod math valid under extreme skew
// invariants: off <= 511+63 = 574 < 2*RING = 640; flush cadence keeps
// live ring entries <= 63 + 2*64 = 191 < RING = 320.
#define ROUND(RECV, BV) { \
    unsigned long long b0_ = __ballot(((BV) & 1u) != 0u); \
    unsigned long long b1_ = __ballot(((BV) & 2u) != 0u); \
    unsigned long long t0_ = ((BV) & 1u) ? b0_ : ~b0_; \
    unsigned long long t1_ = ((BV) & 2u) ? b1_ : ~b1_; \
    unsigned long long mm_ = t0_ & t1_; \
    unsigned rank_ = __builtin_amdgcn_mbcnt_hi((unsigned)(mm_ >> 32), \
                      __builtin_amdgcn_mbcnt_lo((unsigned)mm_, 0u)); \
    unsigned bb_ = ((BV) == 0u) ? base0 : ((BV) == 1u) ? base1 \
                 : ((BV) == 2u) ? base2 : base3; \
    unsigned off_ = bb_ + rank_; \
    unsigned slot_ = off_ < (unsigned)RING ? off_ : off_ - (unsigned)RING; \
    rbase[(BV) * RING + slot_] = (RECV); \
    unsigned long long nb1_ = ~b1_; \
    base0 += (unsigned)__popcll(~b0_ & nb1_); \
    base1 += (unsigned)__popcll( b0_ & nb1_); \
    base2 += (unsigned)__popcll(~b0_ &  b1_); \
    base3 += (unsigned)__popcll( b0_ &  b1_); \
    base0 = base0 < 512u ? base0 : 512u; \
    base1 = base1 < 512u ? base1 : 512u; \
    base2 = base2 < 512u ? base2 : 512u; \
    base3 = base3 < 512u ? base3 : 512u; \
}

#define FLUSHB(BN) \
    while (base##BN - fl##BN >= 64u) { \
        unsigned idx_ = fl##BN + (unsigned)lane; \
        unsigned sl_ = idx_ < (unsigned)RING ? idx_ : idx_ - (unsigned)RING; \
        unsigned v_ = rbase[BN * RING + sl_]; \
        if (idx_ < (unsigned)CAP) seg##BN[idx_] = v_; \
        fl##BN += 64u; \
    }

#define DRAINB(BN) { \
    unsigned rem_ = base##BN - fl##BN; \
    if ((unsigned)lane < rem_) { \
        unsigned idx_ = fl##BN + (unsigned)lane; \
        unsigned sl_ = idx_ < (unsigned)RING ? idx_ : idx_ - (unsigned)RING; \
        if (idx_ < (unsigned)CAP) seg##BN[idx_] = rbase[BN * RING + sl_]; \
    } }

// ---- plan T: pure gather+math kernel -> bf16 w[E] ----
__global__ __launch_bounds__(256)
void kcl_wpass(const float* __restrict__ nf, const int* __restrict__ ei,
               const float* __restrict__ probs, const float* __restrict__ params,
               unsigned short* __restrict__ wout, int E)
{
    int i = (blockIdx.x * 256 + threadIdx.x) * 4;
    const int stride = gridDim.x * 256 * 4;
    for (; i < E; i += stride) {
        int4 s4 = *(const int4*)(ei + i);
        int4 d4 = *(const int4*)(ei + E + i);
        float4 pr = *(const float4*)(probs + i);
        float4 q0 = *(const float4*)(params + 2 * (size_t)i);
        float4 q1 = *(const float4*)(params + 2 * (size_t)i + 4);
        int   ss[4] = {s4.x, s4.y, s4.z, s4.w};
        int   dd[4] = {d4.x, d4.y, d4.z, d4.w};
        float pp[4] = {pr.x, pr.y, pr.z, pr.w};
        float Rk[4] = {q0.x, q0.z, q1.x, q1.z};
        float Xk[4] = {q0.y, q0.w, q1.y, q1.w};

        // issue all 8 gathers first (cached - NO nontemporal, R7 lesson)
        ull ga[4], gb[4];
        #pragma unroll
        for (int e = 0; e < 4; ++e) {
            ga[e] = *(const ull*)(nf + ((size_t)(unsigned)ss[e] << 2));
            gb[e] = *(const ull*)(nf + ((size_t)(unsigned)dd[e] << 2));
        }

        float w[4];
        #pragma unroll
        for (int e = 0; e < 4; ++e) {
            float dr = __uint_as_float((unsigned)ga[e])
                     - __uint_as_float((unsigned)gb[e]);
            float di = __uint_as_float((unsigned)(ga[e] >> 32))
                     - __uint_as_float((unsigned)(gb[e] >> 32));
            float rr = Rk[e] + EPS;
            w[e] = sqrtf(dr * dr + di * di)
                 * rsqrtf(rr * rr + Xk[e] * Xk[e]) * pp[e];
        }
        unsigned p01, p23;
        asm("v_cvt_pk_bf16_f32 %0, %1, %2" : "=v"(p01) : "v"(w[0]), "v"(w[1]));
        asm("v_cvt_pk_bf16_f32 %0, %1, %2" : "=v"(p23) : "v"(w[2]), "v"(w[3]));
        *(uint2*)(wout + i) = make_uint2(p01, p23);
    }
}

// ---- plan T: machinery-only scan (no gathers, no float math) ----
__global__ __launch_bounds__(S_THREADS)
void kcl_scanM(const int* __restrict__ ei, const unsigned short* __restrict__ wbf,
               unsigned* __restrict__ recs, int* __restrict__ counts,
               float* __restrict__ node_tail,
               int E, unsigned B1, unsigned M37, int EPW, int TAILSTART)
{
    __shared__ unsigned ring[S_WPB * NPASS * RING];   // 40960 B
    const int lane = threadIdx.x & 63;
    const int wv   = threadIdx.x >> 6;
    const int wgid = blockIdx.x * S_WPB + wv;
    unsigned* rbase = ring + wv * (NPASS * RING);

    unsigned base0 = 0, base1 = 0, base2 = 0, base3 = 0;
    unsigned fl0 = 0, fl1 = 0, fl2 = 0, fl3 = 0;
    unsigned* seg0 = recs + ((size_t)wgid * NPASS + 0) * CAP;
    unsigned* seg1 = recs + ((size_t)wgid * NPASS + 1) * CAP;
    unsigned* seg2 = recs + ((size_t)wgid * NPASS + 2) * CAP;
    unsigned* seg3 = recs + ((size_t)wgid * NPASS + 3) * CAP;

    const int start = wgid * EPW;
    for (int wb = start; wb < start + EPW; wb += 256) {
        int i = wb + lane * 4;
        int4 s4 = *(const int4*)(ei + i);
        int4 d4 = *(const int4*)(ei + E + i);
        ushort4 w4 = *(const ushort4*)(wbf + i);
        int ss[4] = {s4.x, s4.y, s4.z, s4.w};
        int dd[4] = {d4.x, d4.y, d4.z, d4.w};
        unsigned wb4[4] = {w4.x, w4.y, w4.z, w4.w};

        unsigned rc[8], bk[8];
        #pragma unroll
        for (int e = 0; e < 4; ++e) {
            unsigned s_ = (unsigned)ss[e], d_ = (unsigned)dd[e];
            unsigned bs_ = (unsigned)(((ull)s_ * M37) >> 37);
            unsigned bd_ = (unsigned)(((ull)d_ * M37) >> 37);
            rc[2 * e]     = ((s_ - bs_ * B1) << 16) | wb4[e] | 0x8000u; // -w
            bk[2 * e]     = bs_;
            rc[2 * e + 1] = ((d_ - bd_ * B1) << 16) | wb4[e];           // +w
            bk[2 * e + 1] = bd_;
        }

        ROUND(rc[0], bk[0]); ROUND(rc[1], bk[1]);
        FLUSHB(0) FLUSHB(1) FLUSHB(2) FLUSHB(3)
        ROUND(rc[2], bk[2]); ROUND(rc[3], bk[3]);
        FLUSHB(0) FLUSHB(1) FLUSHB(2) FLUSHB(3)
        ROUND(rc[4], bk[4]); ROUND(rc[5], bk[5]);
        FLUSHB(0) FLUSHB(1) FLUSHB(2) FLUSHB(3)
        ROUND(rc[6], bk[6]); ROUND(rc[7], bk[7]);
        FLUSHB(0) FLUSHB(1) FLUSHB(2) FLUSHB(3)
    }

    DRAINB(0) DRAINB(1) DRAINB(2) DRAINB(3)

    if (lane == 0) {
        int4 c = make_int4((int)(base0 < CAP ? base0 : CAP),
                           (int)(base1 < CAP ? base1 : CAP),
                           (int)(base2 < CAP ? base2 : CAP),
                           (int)(base3 < CAP ? base3 : CAP));
        *(int4*)(counts + wgid * NPASS) = c;
    }

    // tail pool: edges [TAILSTART, E) via global atomics (<=1.7% of edges)
    for (int t = TAILSTART + blockIdx.x * S_THREADS + threadIdx.x; t < E;
         t += S_BLOCKS * S_THREADS) {
        int s = ei[t], d = ei[E + t];
        float wf = __uint_as_float((unsigned)wbf[t] << 16);
        atomicAdd(&node_tail[d],  wf);
        atomicAdd(&node_tail[s], -wf);
    }
}

// ---- plan S scan (R9, proven): fused gather+machinery, used as fallback ----
__global__ __launch_bounds__(S_THREADS)
void kcl_scan5(const float* __restrict__ nf, const int* __restrict__ ei,
               const float* __restrict__ probs, const float* __restrict__ params,
               unsigned* __restrict__ recs, int* __restrict__ counts,
               float* __restrict__ node_tail,
               int E, unsigned B1, unsigned M37, int EPW, int TAILSTART)
{
    __shared__ unsigned ring[S_WPB * NPASS * RING];
    const int lane = threadIdx.x & 63;
    const int wv   = threadIdx.x >> 6;
    const int wgid = blockIdx.x * S_WPB + wv;
    unsigned* rbase = ring + wv * (NPASS * RING);

    unsigned base0 = 0, base1 = 0, base2 = 0, base3 = 0;
    unsigned fl0 = 0, fl1 = 0, fl2 = 0, fl3 = 0;
    unsigned* seg0 = recs + ((size_t)wgid * NPASS + 0) * CAP;
    unsigned* seg1 = recs + ((size_t)wgid * NPASS + 1) * CAP;
    unsigned* seg2 = recs + ((size_t)wgid * NPASS + 2) * CAP;
    unsigned* seg3 = recs + ((size_t)wgid * NPASS + 3) * CAP;

    const int start = wgid * EPW;
    for (int wb = start; wb < start + EPW; wb += 256) {
        int i = wb + lane * 4;
        int4 s4 = *(const int4*)(ei + i);
        int4 d4 = *(const int4*)(ei + E + i);
        float4 pr = *(const float4*)(probs + i);
        float4 q0 = *(const float4*)(params + 2 * (size_t)i);
        float4 q1 = *(const float4*)(params + 2 * (size_t)i + 4);
        int   ss[4] = {s4.x, s4.y, s4.z, s4.w};
        int   dd[4] = {d4.x, d4.y, d4.z, d4.w};
        float pp[4] = {pr.x, pr.y, pr.z, pr.w};
        float Rk[4] = {q0.x, q0.z, q1.x, q1.z};
        float Xk[4] = {q0.y, q0.w, q1.y, q1.w};

        ull ga[4], gb[4];
        #pragma unroll
        for (int e = 0; e < 4; ++e) {
            ga[e] = *(const ull*)(nf + ((size_t)(unsigned)ss[e] << 2));
            gb[e] = *(const ull*)(nf + ((size_t)(unsigned)dd[e] << 2));
        }

        unsigned rc[8], bk[8];
        #pragma unroll
        for (int e = 0; e < 4; ++e) {
            float dr = __uint_as_float((unsigned)ga[e])
                     - __uint_as_float((unsigned)gb[e]);
            float di = __uint_as_float((unsigned)(ga[e] >> 32))
                     - __uint_as_float((unsigned)(gb[e] >> 32));
            float rr = Rk[e] + EPS;
            float w_ = sqrtf(dr * dr + di * di)
                     * rsqrtf(rr * rr + Xk[e] * Xk[e]) * pp[e];
            float nw_ = -w_;
            unsigned pk_;
            asm("v_cvt_pk_bf16_f32 %0, %1, %2" : "=v"(pk_) : "v"(nw_), "v"(w_));
            unsigned s_ = (unsigned)ss[e], d_ = (unsigned)dd[e];
            unsigned bs_ = (unsigned)(((ull)s_ * M37) >> 37);
            unsigned bd_ = (unsigned)(((ull)d_ * M37) >> 37);
            rc[2 * e]     = ((s_ - bs_ * B1) << 16) | (pk_ & 0xFFFFu);
            bk[2 * e]     = bs_;
            rc[2 * e + 1] = ((d_ - bd_ * B1) << 16) | (pk_ >> 16);
            bk[2 * e + 1] = bd_;
        }

        ROUND(rc[0], bk[0]); ROUND(rc[1], bk[1]);
        FLUSHB(0) FLUSHB(1) FLUSHB(2) FLUSHB(3)
        ROUND(rc[2], bk[2]); ROUND(rc[3], bk[3]);
        FLUSHB(0) FLUSHB(1) FLUSHB(2) FLUSHB(3)
        ROUND(rc[4], bk[4]); ROUND(rc[5], bk[5]);
        FLUSHB(0) FLUSHB(1) FLUSHB(2) FLUSHB(3)
        ROUND(rc[6], bk[6]); ROUND(rc[7], bk[7]);
        FLUSHB(0) FLUSHB(1) FLUSHB(2) FLUSHB(3)
    }

    DRAINB(0) DRAINB(1) DRAINB(2) DRAINB(3)

    if (lane == 0) {
        int4 c = make_int4((int)(base0 < CAP ? base0 : CAP),
                           (int)(base1 < CAP ? base1 : CAP),
                           (int)(base2 < CAP ? base2 : CAP),
                           (int)(base3 < CAP ? base3 : CAP));
        *(int4*)(counts + wgid * NPASS) = c;
    }

    for (int t = TAILSTART + blockIdx.x * S_THREADS + threadIdx.x; t < E;
         t += S_BLOCKS * S_THREADS) {
        int s = ei[t], d = ei[E + t];
        float2 q = ((const float2*)params)[t];
        float w = edge_wc(nf, s, d, q.x, q.y, probs[t]);
        atomicAdd(&node_tail[d],  w);
        atomicAdd(&node_tail[s], -w);
    }
}

// ---- bin: wave-per-segment, LDS bins, write partial rows ----
__global__ __launch_bounds__(BIN_THREADS)
void kcl_bin(const unsigned* __restrict__ recs, const int* __restrict__ counts,
             float* __restrict__ partials, int B1)
{
    extern __shared__ float bins[];
    for (int j = threadIdx.x; j < B1; j += BIN_THREADS) bins[j] = 0.0f;
    __syncthreads();

    const int p    = blockIdx.x / RPP;
    const int r    = blockIdx.x % RPP;
    const int SPB  = NWAVE / RPP;           // 128 wave-segments per block
    const int wv   = threadIdx.x >> 6;      // 16 waves
    const int lane = threadIdx.x & 63;
    const int W0   = r * SPB;

    for (int t = wv; t < SPB; t += BIN_THREADS / 64) {
        int seg = (W0 + t) * NPASS + p;
        int cnt = counts[seg];
        const unsigned* bp = recs + (size_t)seg * CAP;
        for (int j = lane; j < cnt; j += 64) {
            unsigned rcd = bp[j];
            atomicAdd(&bins[rcd >> 16], __uint_as_float(rcd << 16));
        }
    }
    __syncthreads();

    float* row = partials + (size_t)blockIdx.x * B1;   // row = p*RPP + r
    for (int j = threadIdx.x; j < B1; j += BIN_THREADS) row[j] = bins[j];
}

// ---- reduce: sum RPP rows + node_tail, square, accumulate ----
__global__ __launch_bounds__(1024)
void kcl_reduce2(const float* __restrict__ partials,
                 const float* __restrict__ node_tail,
                 float* __restrict__ acc, int N, int B1)
{
    int j = blockIdx.x * blockDim.x + threadIdx.x;
    float v = 0.0f;
    if (j < N) {
        int p   = j / B1;
        int bin = j - p * B1;
        const float* col = partials + (size_t)p * RPP * B1 + bin;
        float a0 = 0.f, a1 = 0.f, a2 = 0.f, a3 = 0.f;
        for (int rr = 0; rr < RPP; rr += 4) {
            a0 += col[(size_t)(rr + 0) * B1];
            a1 += col[(size_t)(rr + 1) * B1];
            a2 += col[(size_t)(rr + 2) * B1];
            a3 += col[(size_t)(rr + 3) * B1];
        }
        v = (a0 + a1) + (a2 + a3) + node_tail[j];
    }
    float sq = v * v;
    for (int off = 32; off > 0; off >>= 1)
        sq += __shfl_down(sq, off, 64);
    __shared__ float wsum[16];
    int lane = threadIdx.x & 63;
    int wid  = threadIdx.x >> 6;
    if (lane == 0) wsum[wid] = sq;
    __syncthreads();
    if (threadIdx.x == 0) {
        float t = 0.0f;
        int nw = blockDim.x >> 6;
        for (int w = 0; w < nw; ++w) t += wsum[w];
        atomicAdd(acc, t);
    }
}

__global__ void kcl_final(const float* __restrict__ acc, float* __restrict__ out,
                          float invN)
{
    if (blockIdx.x == 0 && threadIdx.x == 0)
        out[0] = acc[0] * invN;
}

// ================= plan A fallback (R3 structure) ==================
#define A_BINS 25600
#define A_PBLK 256
#define A_PTHR 1024

__global__ __launch_bounds__(A_PTHR)
void kcl_pass(const float* __restrict__ nf, const int* __restrict__ ei,
              const float* __restrict__ probs, const float* __restrict__ params,
              const float* __restrict__ wc_in, float* __restrict__ wc_out,
              float* __restrict__ partials, int E, int lo, int cnt)
{
    extern __shared__ float bins[];
    for (int j = threadIdx.x; j < cnt; j += A_PTHR) bins[j] = 0.0f;
    __syncthreads();

    int i0     = (blockIdx.x * A_PTHR + threadIdx.x) * 4;
    int stride = gridDim.x * A_PTHR * 4;
    for (int i = i0; i < E; i += stride) {
        if (i + 4 <= E) {
            int4 s4 = *(const int4*)(ei + i);
            int4 d4 = *(const int4*)(ei + E + i);
            int ss[4] = {s4.x, s4.y, s4.z, s4.w};
            int dd[4] = {d4.x, d4.y, d4.z, d4.w};
            float w[4];
            if (wc_in) {
                float4 w4 = *(const float4*)(wc_in + i);
                w[0] = w4.x; w[1] = w4.y; w[2] = w4.z; w[3] = w4.w;
            } else {
                float4 pr = *(const float4*)(probs + i);
                float pp[4] = {pr.x, pr.y, pr.z, pr.w};
                float4 q0 = *(const float4*)(params + 2 * (size_t)i);
                float4 q1 = *(const float4*)(params + 2 * (size_t)i + 4);
                float Rk[4] = {q0.x, q0.z, q1.x, q1.z};
                float Xk[4] = {q0.y, q0.w, q1.y, q1.w};
                #pragma unroll
                for (int k = 0; k < 4; ++k)
                    w[k] = edge_wc(nf, ss[k], dd[k], Rk[k], Xk[k], pp[k]);
                if (wc_out)
                    *(float4*)(wc_out + i) = make_float4(w[0], w[1], w[2], w[3]);
            }
            #pragma unroll
            for (int k = 0; k < 4; ++k) {
                unsigned rs = (unsigned)(ss[k] - lo);
                if (rs < (unsigned)cnt) atomicAdd(&bins[rs], -w[k]);
                unsigned rd = (unsigned)(dd[k] - lo);
                if (rd < (unsigned)cnt) atomicAdd(&bins[rd],  w[k]);
            }
        } else {
            for (int t = i; t < E; ++t) {
                int s = ei[t], d = ei[E + t];
                float w;
                if (wc_in) w = wc_in[t];
                else {
                    float2 q = ((const float2*)params)[t];
                    w = edge_wc(nf, s, d, q.x, q.y, probs[t]);
                    if (wc_out) wc_out[t] = w;
                }
                unsigned rs = (unsigned)(s - lo);
                if (rs < (unsigned)cnt) atomicAdd(&bins[rs], -w);
                unsigned rd = (unsigned)(d - lo);
                if (rd < (unsigned)cnt) atomicAdd(&bins[rd],  w);
            }
        }
    }
    __syncthreads();
    float* row = partials + (size_t)blockIdx.x * A_BINS;
    for (int j = threadIdx.x; j < cnt; j += A_PTHR) row[j] = bins[j];
}

__global__ __launch_bounds__(1024)
void kcl_reduceA(const float* __restrict__ partials, float* __restrict__ acc, int cnt)
{
    int j = blockIdx.x * blockDim.x + threadIdx.x;
    float v = 0.0f;
    if (j < cnt) {
        const float* p = partials + j;
        float a0 = 0.f, a1 = 0.f, a2 = 0.f, a3 = 0.f;
        for (int b = 0; b < A_PBLK; b += 4) {
            a0 += p[(size_t)(b + 0) * A_BINS];
            a1 += p[(size_t)(b + 1) * A_BINS];
            a2 += p[(size_t)(b + 2) * A_BINS];
            a3 += p[(size_t)(b + 3) * A_BINS];
        }
        v = (a0 + a1) + (a2 + a3);
    }
    float sq = v * v;
    for (int off = 32; off > 0; off >>= 1)
        sq += __shfl_down(sq, off, 64);
    __shared__ float wsum[16];
    int lane = threadIdx.x & 63;
    int wid  = threadIdx.x >> 6;
    if (lane == 0) wsum[wid] = sq;
    __syncthreads();
    if (threadIdx.x == 0) {
        float t = 0.0f;
        int nw = blockDim.x >> 6;
        for (int w = 0; w < nw; ++w) t += wsum[w];
        atomicAdd(acc, t);
    }
}

// ---- plan C fallback: global atomics (R2) ----
__global__ void kcl_edge_atomic(const float* __restrict__ nf,
                                const int* __restrict__ ei,
                                const float* __restrict__ probs,
                                const float* __restrict__ params,
                                float* __restrict__ node_sum, int E)
{
    int i = blockIdx.x * blockDim.x + threadIdx.x;
    int stride = gridDim.x * blockDim.x;
    for (; i < E; i += stride) {
        int s = ei[i], d = ei[E + i];
        float2 q = ((const float2*)params)[i];
        float w = edge_wc(nf, s, d, q.x, q.y, probs[i]);
        atomicAdd(&node_sum[d],  w);
        atomicAdd(&node_sum[s], -w);
    }
}

__global__ void kcl_sos(const float* __restrict__ node_sum,
                        float* __restrict__ acc, int N)
{
    int i = blockIdx.x * blockDim.x + threadIdx.x;
    int stride = gridDim.x * blockDim.x;
    float s = 0.0f;
    for (; i < N; i += stride) { float v = node_sum[i]; s += v * v; }
    for (int off = 32; off > 0; off >>= 1)
        s += __shfl_down(s, off, 64);
    __shared__ float wsum[8];
    int lane = threadIdx.x & 63;
    int wid  = threadIdx.x >> 6;
    if (lane == 0) wsum[wid] = s;
    __syncthreads();
    if (threadIdx.x == 0) {
        float t = 0.0f;
        int nw = (blockDim.x + 63) >> 6;
        for (int w = 0; w < nw; ++w) t += wsum[w];
        atomicAdd(acc, t);
    }
}

// ===========================================================================
static inline size_t align256(size_t x) { return (x + 255) / 256 * 256; }

extern "C" void kernel_launch(void* const* d_in, const int* in_sizes, int n_in,
                              void* d_out, int out_size, void* d_ws, size_t ws_size,
                              hipStream_t stream)
{
    const float* nf     = (const float*)d_in[0];
    const int*   ei     = (const int*)d_in[1];
    const float* probs  = (const float*)d_in[2];
    const float* params = (const float*)d_in[3];
    float*       out    = (float*)d_out;

    const int N = in_sizes[0] / 4;
    const int E = in_sizes[2];

    // ---- shared sizing (plans T and S) ----
    const unsigned B1 = (unsigned)((N + NPASS - 1) / NPASS);
    const unsigned M37 = (unsigned)(((1ULL << 37) + B1 - 1) / B1);
    const int EPW = (E / (NWAVE * 256)) * 256;      // full chunks per wave
    const int TAILSTART = NWAVE * EPW;

    size_t off_tail     = 256;                                   // acc at 0
    size_t off_counts   = off_tail + align256((size_t)N * 4);
    size_t off_partials = off_counts + align256((size_t)NWAVE * NPASS * 4);
    size_t off_recs     = off_partials + align256((size_t)NPASS * RPP * B1 * 4);
    size_t off_w        = off_recs + align256((size_t)NWAVE * NPASS * CAP * 4);
    size_t need_S = off_w;                                       // without w
    size_t need_T = off_w + align256((size_t)E * 2);             // + bf16 w

    const bool geomOK = (B1 >= 1) && (B1 <= B1MAX) && (N >= 1) &&
                        ((size_t)N <= (size_t)NPASS * B1) && (E >= 0);
    const bool okT = geomOK && (ws_size >= need_T) && (E % 4 == 0) && (E > 0);
    const bool okS = geomOK && (ws_size >= need_S);

    if (okT || okS) {
        float*    acc       = (float*)d_ws;
        float*    node_tail = (float*)((char*)d_ws + off_tail);
        int*      counts    = (int*)((char*)d_ws + off_counts);
        float*    partials  = (float*)((char*)d_ws + off_partials);
        unsigned* recs      = (unsigned*)((char*)d_ws + off_recs);

        // zero acc + node_tail (contiguous prefix)
        hipMemsetAsync(d_ws, 0, off_tail + (size_t)N * 4, stream);

        if (okT) {
            unsigned short* wbf = (unsigned short*)((char*)d_ws + off_w);
            int wgrid = (E / 4 + 255) / 256;
            if (wgrid > 8192) wgrid = 8192;
            kcl_wpass<<<wgrid, 256, 0, stream>>>(nf, ei, probs, params, wbf, E);
            kcl_scanM<<<S_BLOCKS, S_THREADS, 0, stream>>>(
                ei, wbf, recs, counts, node_tail, E, B1, M37, EPW, TAILSTART);
        } else {
            kcl_scan5<<<S_BLOCKS, S_THREADS, 0, stream>>>(
                nf, ei, probs, params, recs, counts, node_tail,
                E, B1, M37, EPW, TAILSTART);
        }

        kcl_bin<<<NPASS * RPP, BIN_THREADS, (size_t)B1 * sizeof(float), stream>>>(
            recs, counts, partials, (int)B1);

        int rgrid = (N + 1023) / 1024;
        kcl_reduce2<<<rgrid, 1024, 0, stream>>>(partials, node_tail, acc, N, (int)B1);

        kcl_final<<<1, 64, 0, stream>>>(acc, out, 1.0f / (float)N);
        return;
    }

    // ---- plan A (R3) ----
    const size_t a_partials = (size_t)A_PBLK * A_BINS * sizeof(float);
    const size_t need_A = 16 + a_partials;
    const size_t need_Awc = need_A + (size_t)E * sizeof(float);
    if (ws_size >= need_A) {
        float* acc      = (float*)d_ws;
        float* partials = (float*)((char*)d_ws + 16);
        float* wc       = (ws_size >= need_Awc)
                            ? (float*)((char*)d_ws + 16 + a_partials) : nullptr;
        hipMemsetAsync(acc, 0, sizeof(float), stream);
        const int npass = (N + A_BINS - 1) / A_BINS;
        for (int p = 0; p < npass; ++p) {
            int lo  = p * A_BINS;
            int cnt = (N - lo < A_BINS) ? (N - lo) : A_BINS;
            const float* wc_in  = (wc && p > 0) ? wc : nullptr;
            float*       wc_out = (wc && p == 0) ? wc : nullptr;
            kcl_pass<<<A_PBLK, A_PTHR, A_BINS * sizeof(float), stream>>>(
                nf, ei, probs, params, wc_in, wc_out, partials, E, lo, cnt);
            int rgrid = (cnt + 1023) / 1024;
            kcl_reduceA<<<rgrid, 1024, 0, stream>>>(partials, acc, cnt);
        }
        kcl_final<<<1, 64, 0, stream>>>(acc, out, 1.0f / (float)N);
        return;
    }

    // ---- plan C (R2) ----
    {
        float* node_sum = (float*)d_ws;
        float* acc      = node_sum + N;
        hipMemsetAsync(d_ws, 0, (size_t)(N + 1) * sizeof(float), stream);
        int grid = (E + 255) / 256; if (grid > 4096) grid = 4096;
        kcl_edge_atomic<<<grid, 256, 0, stream>>>(nf, ei, probs, params, node_sum, E);
        int rgrid = (N + 255) / 256; if (rgrid > 256) rgrid = 256;
        kcl_sos<<<rgrid, 256, 0, stream>>>(node_sum, acc, N);
        kcl_final<<<1, 64, 0, stream>>>(acc, out, 1.0f / (float)N);
    }
}

// Round 11
// 155.203 us; speedup vs baseline: 1.1428x; 1.1428x over previous
//
#include <hip/hip_runtime.h>

// ---------------------------------------------------------------------------
// KCL: per-edge weighted current, scatter (+dst, -src), mean(node_sum^2).
//
// FINAL (R11) = R6's measured-best config (155.0 us), reverted after R10's
// attribution experiment:
//   - fused scan3: gathers + ballot-ranked record machinery overlap (116 us;
//     pure-gather wall alone measured 88 us in R10 -> ~70% of machinery hides)
//   - bin: wave-per-segment LDS binning (18 us)
//   - reduce + final (~20 us incl. overheads)
// Falsified levers (R6/R7/R9/R10): VALU machinery cuts, occupancy, SW
// pipelining, nontemporal loads (L2 bypass!), gather/machinery split.
// Structural wall: divergent L1/TA request throughput ~7.4 cyc per
// 64-lane divergent vector load (25.6M lane-requests = 88 us).
//
// Inputs (harness converts integer inputs to int32):
//   d_in[0] node_features float32 [N,4] (cols 0,1), d_in[1] edge_index int32 [2,E]
//   d_in[2] edge_probs float32 [E],  d_in[3] edge_params float32 [E,2]
// ---------------------------------------------------------------------------

#define EPS 1e-6f

// ---- plan S geometry ----
#define NPASS       4
#define S_BLOCKS    1024
#define S_THREADS   512
#define S_WPB       (S_THREADS / 64)     // 8 waves/block
#define NWAVE       (S_BLOCKS * S_WPB)   // 8192
#define RING        320                  // LDS ring slots per (wave,bucket)
#define CAP         472                  // records per (wave,bucket) segment
#define RPP         64                   // bin blocks per pass
#define BIN_THREADS 1024
#define B1MAX       25600

typedef unsigned long long ull;

__device__ __forceinline__ float edge_wc(const float* __restrict__ nf,
                                         int s, int d, float R, float X, float p)
{
    float2 vs = *(const float2*)(nf + ((size_t)s << 2));
    float2 vd = *(const float2*)(nf + ((size_t)d << 2));
    float dr = vs.x - vd.x;
    float di = vs.y - vd.y;
    float rr = R + EPS;
    return sqrtf(dr * dr + di * di) * rsqrtf(rr * rr + X * X) * p;
}

// invariants: clamp 512 >= CAP; off <= 511+63 = 574 < 2*RING = 640;
// flush cadence (every 2 PROCESS = 4 ROUNDs) keeps live <= 63+256 = 319 < 320.
#define ROUND(RECV, BV) { \
    unsigned long long b0_ = __ballot(((BV) & 1u) != 0u); \
    unsigned long long b1_ = __ballot(((BV) & 2u) != 0u); \
    unsigned long long t0_ = ((BV) & 1u) ? b0_ : ~b0_; \
    unsigned long long t1_ = ((BV) & 2u) ? b1_ : ~b1_; \
    unsigned long long mm_ = t0_ & t1_; \
    unsigned rank_ = __builtin_amdgcn_mbcnt_hi((unsigned)(mm_ >> 32), \
                      __builtin_amdgcn_mbcnt_lo((unsigned)mm_, 0u)); \
    unsigned bb_ = ((BV) == 0u) ? base0 : ((BV) == 1u) ? base1 \
                 : ((BV) == 2u) ? base2 : base3; \
    unsigned off_ = bb_ + rank_; \
    unsigned slot_ = off_ < (unsigned)RING ? off_ : off_ - (unsigned)RING; \
    rbase[(BV) * RING + slot_] = (RECV); \
    unsigned long long nb1_ = ~b1_; \
    base0 += (unsigned)__popcll(~b0_ & nb1_); \
    base1 += (unsigned)__popcll( b0_ & nb1_); \
    base2 += (unsigned)__popcll(~b0_ &  b1_); \
    base3 += (unsigned)__popcll( b0_ &  b1_); \
    base0 = base0 < 512u ? base0 : 512u; \
    base1 = base1 < 512u ? base1 : 512u; \
    base2 = base2 < 512u ? base2 : 512u; \
    base3 = base3 < 512u ? base3 : 512u; \
}

#define FLUSHB(BN) \
    while (base##BN - fl##BN >= 64u) { \
        unsigned idx_ = fl##BN + (unsigned)lane; \
        unsigned sl_ = idx_ < (unsigned)RING ? idx_ : idx_ - (unsigned)RING; \
        unsigned v_ = rbase[BN * RING + sl_]; \
        if (idx_ < (unsigned)CAP) seg##BN[idx_] = v_; \
        fl##BN += 64u; \
    }

#define DRAINB(BN) { \
    unsigned rem_ = base##BN - fl##BN; \
    if ((unsigned)lane < rem_) { \
        unsigned idx_ = fl##BN + (unsigned)lane; \
        unsigned sl_ = idx_ < (unsigned)RING ? idx_ : idx_ - (unsigned)RING; \
        if (idx_ < (unsigned)CAP) seg##BN[idx_] = rbase[BN * RING + sl_]; \
    } }

#define PROCESS(e) { \
    int s_ = ss[e], d_ = dd[e]; \
    float w_ = edge_wc(nf, s_, d_, Rk[e], Xk[e], pp[e]); \
    float nw_ = -w_; \
    unsigned pk_; \
    asm("v_cvt_pk_bf16_f32 %0, %1, %2" : "=v"(pk_) : "v"(nw_), "v"(w_)); \
    unsigned bs_ = (unsigned)(((unsigned long long)(unsigned)s_ * M37) >> 37); \
    unsigned bd_ = (unsigned)(((unsigned long long)(unsigned)d_ * M37) >> 37); \
    unsigned rs_ = (((unsigned)s_ - bs_ * B1) << 16) | (pk_ & 0xFFFFu); \
    unsigned rd_ = (((unsigned)d_ - bd_ * B1) << 16) | (pk_ >> 16); \
    ROUND(rs_, bs_); \
    ROUND(rd_, bd_); \
}

// ---- plan S scan: 3 full chunks per wave + global-atomic tail pool ----
__global__ __launch_bounds__(S_THREADS)
void kcl_scan3(const float* __restrict__ nf, const int* __restrict__ ei,
               const float* __restrict__ probs, const float* __restrict__ params,
               unsigned* __restrict__ recs, int* __restrict__ counts,
               float* __restrict__ node_tail,
               int E, unsigned B1, unsigned M37, int EPW, int TAILSTART)
{
    __shared__ unsigned ring[S_WPB * NPASS * RING];   // 40960 B
    const int lane = threadIdx.x & 63;
    const int wv   = threadIdx.x >> 6;
    const int wgid = blockIdx.x * S_WPB + wv;
    unsigned* rbase = ring + wv * (NPASS * RING);

    unsigned base0 = 0, base1 = 0, base2 = 0, base3 = 0;
    unsigned fl0 = 0, fl1 = 0, fl2 = 0, fl3 = 0;
    unsigned* seg0 = recs + ((size_t)wgid * NPASS + 0) * CAP;
    unsigned* seg1 = recs + ((size_t)wgid * NPASS + 1) * CAP;
    unsigned* seg2 = recs + ((size_t)wgid * NPASS + 2) * CAP;
    unsigned* seg3 = recs + ((size_t)wgid * NPASS + 3) * CAP;

    const int start = wgid * EPW;
    for (int wb = start; wb < start + EPW; wb += 256) {
        int i = wb + lane * 4;
        int4 s4 = *(const int4*)(ei + i);
        int4 d4 = *(const int4*)(ei + E + i);
        float4 pr = *(const float4*)(probs + i);
        float4 q0 = *(const float4*)(params + 2 * (size_t)i);
        float4 q1 = *(const float4*)(params + 2 * (size_t)i + 4);
        int   ss[4] = {s4.x, s4.y, s4.z, s4.w};
        int   dd[4] = {d4.x, d4.y, d4.z, d4.w};
        float pp[4] = {pr.x, pr.y, pr.z, pr.w};
        float Rk[4] = {q0.x, q0.z, q1.x, q1.z};
        float Xk[4] = {q0.y, q0.w, q1.y, q1.w};

        PROCESS(0)
        PROCESS(1)
        FLUSHB(0) FLUSHB(1) FLUSHB(2) FLUSHB(3)
        PROCESS(2)
        PROCESS(3)
        FLUSHB(0) FLUSHB(1) FLUSHB(2) FLUSHB(3)
    }

    DRAINB(0) DRAINB(1) DRAINB(2) DRAINB(3)

    if (lane == 0) {
        int4 c = make_int4((int)(base0 < CAP ? base0 : CAP),
                           (int)(base1 < CAP ? base1 : CAP),
                           (int)(base2 < CAP ? base2 : CAP),
                           (int)(base3 < CAP ? base3 : CAP));
        *(int4*)(counts + wgid * NPASS) = c;
    }

    // tail pool: edges [TAILSTART, E) via global atomics (<=1.7% of edges)
    for (int t = TAILSTART + blockIdx.x * S_THREADS + threadIdx.x; t < E;
         t += S_BLOCKS * S_THREADS) {
        int s = ei[t], d = ei[E + t];
        float2 q = ((const float2*)params)[t];
        float w = edge_wc(nf, s, d, q.x, q.y, probs[t]);
        atomicAdd(&node_tail[d],  w);
        atomicAdd(&node_tail[s], -w);
    }
}

// ---- plan S bin: wave-per-segment, LDS bins, write partial rows ----
__global__ __launch_bounds__(BIN_THREADS)
void kcl_bin(const unsigned* __restrict__ recs, const int* __restrict__ counts,
             float* __restrict__ partials, int B1)
{
    extern __shared__ float bins[];
    for (int j = threadIdx.x; j < B1; j += BIN_THREADS) bins[j] = 0.0f;
    __syncthreads();

    const int p    = blockIdx.x / RPP;
    const int r    = blockIdx.x % RPP;
    const int SPB  = NWAVE / RPP;           // 128 wave-segments per block
    const int wv   = threadIdx.x >> 6;      // 16 waves
    const int lane = threadIdx.x & 63;
    const int W0   = r * SPB;

    for (int t = wv; t < SPB; t += BIN_THREADS / 64) {
        int seg = (W0 + t) * NPASS + p;
        int cnt = counts[seg];
        const unsigned* bp = recs + (size_t)seg * CAP;
        for (int j = lane; j < cnt; j += 64) {
            unsigned rcd = bp[j];
            atomicAdd(&bins[rcd >> 16], __uint_as_float(rcd << 16));
        }
    }
    __syncthreads();

    float* row = partials + (size_t)blockIdx.x * B1;   // row = p*RPP + r
    for (int j = threadIdx.x; j < B1; j += BIN_THREADS) row[j] = bins[j];
}

// ---- plan S reduce: sum RPP rows + node_tail, square, accumulate ----
__global__ __launch_bounds__(1024)
void kcl_reduce2(const float* __restrict__ partials,
                 const float* __restrict__ node_tail,
                 float* __restrict__ acc, int N, int B1)
{
    int j = blockIdx.x * blockDim.x + threadIdx.x;
    float v = 0.0f;
    if (j < N) {
        int p   = j / B1;
        int bin = j - p * B1;
        const float* col = partials + (size_t)p * RPP * B1 + bin;
        float a0 = 0.f, a1 = 0.f, a2 = 0.f, a3 = 0.f;
        for (int rr = 0; rr < RPP; rr += 4) {
            a0 += col[(size_t)(rr + 0) * B1];
            a1 += col[(size_t)(rr + 1) * B1];
            a2 += col[(size_t)(rr + 2) * B1];
            a3 += col[(size_t)(rr + 3) * B1];
        }
        v = (a0 + a1) + (a2 + a3) + node_tail[j];
    }
    float sq = v * v;
    for (int off = 32; off > 0; off >>= 1)
        sq += __shfl_down(sq, off, 64);
    __shared__ float wsum[16];
    int lane = threadIdx.x & 63;
    int wid  = threadIdx.x >> 6;
    if (lane == 0) wsum[wid] = sq;
    __syncthreads();
    if (threadIdx.x == 0) {
        float t = 0.0f;
        int nw = blockDim.x >> 6;
        for (int w = 0; w < nw; ++w) t += wsum[w];
        atomicAdd(acc, t);
    }
}

__global__ void kcl_final(const float* __restrict__ acc, float* __restrict__ out,
                          float invN)
{
    if (blockIdx.x == 0 && threadIdx.x == 0)
        out[0] = acc[0] * invN;
}

// ================= plan A fallback (R3 structure) ==================
#define A_BINS 25600
#define A_PBLK 256
#define A_PTHR 1024

__global__ __launch_bounds__(A_PTHR)
void kcl_pass(const float* __restrict__ nf, const int* __restrict__ ei,
              const float* __restrict__ probs, const float* __restrict__ params,
              const float* __restrict__ wc_in, float* __restrict__ wc_out,
              float* __restrict__ partials, int E, int lo, int cnt)
{
    extern __shared__ float bins[];
    for (int j = threadIdx.x; j < cnt; j += A_PTHR) bins[j] = 0.0f;
    __syncthreads();

    int i0     = (blockIdx.x * A_PTHR + threadIdx.x) * 4;
    int stride = gridDim.x * A_PTHR * 4;
    for (int i = i0; i < E; i += stride) {
        if (i + 4 <= E) {
            int4 s4 = *(const int4*)(ei + i);
            int4 d4 = *(const int4*)(ei + E + i);
            int ss[4] = {s4.x, s4.y, s4.z, s4.w};
            int dd[4] = {d4.x, d4.y, d4.z, d4.w};
            float w[4];
            if (wc_in) {
                float4 w4 = *(const float4*)(wc_in + i);
                w[0] = w4.x; w[1] = w4.y; w[2] = w4.z; w[3] = w4.w;
            } else {
                float4 pr = *(const float4*)(probs + i);
                float pp[4] = {pr.x, pr.y, pr.z, pr.w};
                float4 q0 = *(const float4*)(params + 2 * (size_t)i);
                float4 q1 = *(const float4*)(params + 2 * (size_t)i + 4);
                float Rk[4] = {q0.x, q0.z, q1.x, q1.z};
                float Xk[4] = {q0.y, q0.w, q1.y, q1.w};
                #pragma unroll
                for (int k = 0; k < 4; ++k)
                    w[k] = edge_wc(nf, ss[k], dd[k], Rk[k], Xk[k], pp[k]);
                if (wc_out)
                    *(float4*)(wc_out + i) = make_float4(w[0], w[1], w[2], w[3]);
            }
            #pragma unroll
            for (int k = 0; k < 4; ++k) {
                unsigned rs = (unsigned)(ss[k] - lo);
                if (rs < (unsigned)cnt) atomicAdd(&bins[rs], -w[k]);
                unsigned rd = (unsigned)(dd[k] - lo);
                if (rd < (unsigned)cnt) atomicAdd(&bins[rd],  w[k]);
            }
        } else {
            for (int t = i; t < E; ++t) {
                int s = ei[t], d = ei[E + t];
                float w;
                if (wc_in) w = wc_in[t];
                else {
                    float2 q = ((const float2*)params)[t];
                    w = edge_wc(nf, s, d, q.x, q.y, probs[t]);
                    if (wc_out) wc_out[t] = w;
                }
                unsigned rs = (unsigned)(s - lo);
                if (rs < (unsigned)cnt) atomicAdd(&bins[rs], -w);
                unsigned rd = (unsigned)(d - lo);
                if (rd < (unsigned)cnt) atomicAdd(&bins[rd],  w);
            }
        }
    }
    __syncthreads();
    float* row = partials + (size_t)blockIdx.x * A_BINS;
    for (int j = threadIdx.x; j < cnt; j += A_PTHR) row[j] = bins[j];
}

__global__ __launch_bounds__(1024)
void kcl_reduceA(const float* __restrict__ partials, float* __restrict__ acc, int cnt)
{
    int j = blockIdx.x * blockDim.x + threadIdx.x;
    float v = 0.0f;
    if (j < cnt) {
        const float* p = partials + j;
        float a0 = 0.f, a1 = 0.f, a2 = 0.f, a3 = 0.f;
        for (int b = 0; b < A_PBLK; b += 4) {
            a0 += p[(size_t)(b + 0) * A_BINS];
            a1 += p[(size_t)(b + 1) * A_BINS];
            a2 += p[(size_t)(b + 2) * A_BINS];
            a3 += p[(size_t)(b + 3) * A_BINS];
        }
        v = (a0 + a1) + (a2 + a3);
    }
    float sq = v * v;
    for (int off = 32; off > 0; off >>= 1)
        sq += __shfl_down(sq, off, 64);
    __shared__ float wsum[16];
    int lane = threadIdx.x & 63;
    int wid  = threadIdx.x >> 6;
    if (lane == 0) wsum[wid] = sq;
    __syncthreads();
    if (threadIdx.x == 0) {
        float t = 0.0f;
        int nw = blockDim.x >> 6;
        for (int w = 0; w < nw; ++w) t += wsum[w];
        atomicAdd(acc, t);
    }
}

// ---- plan C fallback: global atomics (R2) ----
__global__ void kcl_edge_atomic(const float* __restrict__ nf,
                                const int* __restrict__ ei,
                                const float* __restrict__ probs,
                                const float* __restrict__ params,
                                float* __restrict__ node_sum, int E)
{
    int i = blockIdx.x * blockDim.x + threadIdx.x;
    int stride = gridDim.x * blockDim.x;
    for (; i < E; i += stride) {
        int s = ei[i], d = ei[E + i];
        float2 q = ((const float2*)params)[i];
        float w = edge_wc(nf, s, d, q.x, q.y, probs[i]);
        atomicAdd(&node_sum[d],  w);
        atomicAdd(&node_sum[s], -w);
    }
}

__global__ void kcl_sos(const float* __restrict__ node_sum,
                        float* __restrict__ acc, int N)
{
    int i = blockIdx.x * blockDim.x + threadIdx.x;
    int stride = gridDim.x * blockDim.x;
    float s = 0.0f;
    for (; i < N; i += stride) { float v = node_sum[i]; s += v * v; }
    for (int off = 32; off > 0; off >>= 1)
        s += __shfl_down(s, off, 64);
    __shared__ float wsum[8];
    int lane = threadIdx.x & 63;
    int wid  = threadIdx.x >> 6;
    if (lane == 0) wsum[wid] = s;
    __syncthreads();
    if (threadIdx.x == 0) {
        float t = 0.0f;
        int nw = (blockDim.x + 63) >> 6;
        for (int w = 0; w < nw; ++w) t += wsum[w];
        atomicAdd(acc, t);
    }
}

// ===========================================================================
static inline size_t align256(size_t x) { return (x + 255) / 256 * 256; }

extern "C" void kernel_launch(void* const* d_in, const int* in_sizes, int n_in,
                              void* d_out, int out_size, void* d_ws, size_t ws_size,
                              hipStream_t stream)
{
    const float* nf     = (const float*)d_in[0];
    const int*   ei     = (const int*)d_in[1];
    const float* probs  = (const float*)d_in[2];
    const float* params = (const float*)d_in[3];
    float*       out    = (float*)d_out;

    const int N = in_sizes[0] / 4;
    const int E = in_sizes[2];

    // ---- plan S sizing ----
    const unsigned B1 = (unsigned)((N + NPASS - 1) / NPASS);
    const unsigned M37 = (unsigned)(((1ULL << 37) + B1 - 1) / B1);
    const int EPW = (E / (NWAVE * 256)) * 256;      // full chunks per wave
    const int TAILSTART = NWAVE * EPW;

    size_t off_tail     = 256;                                   // acc at 0
    size_t off_counts   = off_tail + align256((size_t)N * 4);
    size_t off_partials = off_counts + align256((size_t)NWAVE * NPASS * 4);
    size_t off_recs     = off_partials + align256((size_t)NPASS * RPP * B1 * 4);
    size_t need_S = off_recs + (size_t)NWAVE * NPASS * CAP * 4;

    const bool okS = (ws_size >= need_S) && (B1 >= 1) && (B1 <= B1MAX) &&
                     (N >= 1) && ((size_t)N <= (size_t)NPASS * B1) && (E >= 0);

    if (okS) {
        float*    acc       = (float*)d_ws;
        float*    node_tail = (float*)((char*)d_ws + off_tail);
        int*      counts    = (int*)((char*)d_ws + off_counts);
        float*    partials  = (float*)((char*)d_ws + off_partials);
        unsigned* recs      = (unsigned*)((char*)d_ws + off_recs);

        // zero acc + node_tail (contiguous prefix)
        hipMemsetAsync(d_ws, 0, off_tail + (size_t)N * 4, stream);

        kcl_scan3<<<S_BLOCKS, S_THREADS, 0, stream>>>(
            nf, ei, probs, params, recs, counts, node_tail,
            E, B1, M37, EPW, TAILSTART);

        kcl_bin<<<NPASS * RPP, BIN_THREADS, (size_t)B1 * sizeof(float), stream>>>(
            recs, counts, partials, (int)B1);

        int rgrid = (N + 1023) / 1024;
        kcl_reduce2<<<rgrid, 1024, 0, stream>>>(partials, node_tail, acc, N, (int)B1);

        kcl_final<<<1, 64, 0, stream>>>(acc, out, 1.0f / (float)N);
        return;
    }

    // ---- plan A (R3) ----
    const size_t a_partials = (size_t)A_PBLK * A_BINS * sizeof(float);
    const size_t need_A = 16 + a_partials;
    const size_t need_Awc = need_A + (size_t)E * sizeof(float);
    if (ws_size >= need_A) {
        float* acc      = (float*)d_ws;
        float* partials = (float*)((char*)d_ws + 16);
        float* wc       = (ws_size >= need_Awc)
                            ? (float*)((char*)d_ws + 16 + a_partials) : nullptr;
        hipMemsetAsync(acc, 0, sizeof(float), stream);
        const int npass = (N + A_BINS - 1) / A_BINS;
        for (int p = 0; p < npass; ++p) {
            int lo  = p * A_BINS;
            int cnt = (N - lo < A_BINS) ? (N - lo) : A_BINS;
            const float* wc_in  = (wc && p > 0) ? wc : nullptr;
            float*       wc_out = (wc && p == 0) ? wc : nullptr;
            kcl_pass<<<A_PBLK, A_PTHR, A_BINS * sizeof(float), stream>>>(
                nf, ei, probs, params, wc_in, wc_out, partials, E, lo, cnt);
            int rgrid = (cnt + 1023) / 1024;
            kcl_reduceA<<<rgrid, 1024, 0, stream>>>(partials, acc, cnt);
        }
        kcl_final<<<1, 64, 0, stream>>>(acc, out, 1.0f / (float)N);
        return;
    }

    // ---- plan C (R2) ----
    {
        float* node_sum = (float*)d_ws;
        float* acc      = node_sum + N;
        hipMemsetAsync(d_ws, 0, (size_t)(N + 1) * sizeof(float), stream);
        int grid = (E + 255) / 256; if (grid > 4096) grid = 4096;
        kcl_edge_atomic<<<grid, 256, 0, stream>>>(nf, ei, probs, params, node_sum, E);
        int rgrid = (N + 255) / 256; if (rgrid > 256) rgrid = 256;
        kcl_sos<<<rgrid, 256, 0, stream>>>(node_sum, acc, N);
        kcl_final<<<1, 64, 0, stream>>>(acc, out, 1.0f / (float)N);
    }
}